// Round 5
// baseline (5872.689 us; speedup 1.0000x reference)
//
#include <hip/hip_runtime.h>
#include <hip/hip_bf16.h>
#include <math.h>

#define M_SIZE 262144
#define D 128
#define B 1024
#define K_TOP 256
#define MARGIN 0.1f
#define TEMP 1.0f   // max(1, log(0.2*256)/40) = 1.0

// d_out layout (all float32, concatenated in return order)
#define OUT_YHAT 0
#define OUT_SOFTMAX (B)                         // 1024
#define OUT_LOSS (B + B * K_TOP)                // 263168
#define OUT_KEYS (OUT_LOSS + 1)                 // 263169
#define OUT_VALUES (OUT_KEYS + M_SIZE * D)      // 33817601
#define OUT_AGE (OUT_VALUES + M_SIZE)           // 34079745

// ---------------- monotonic f32 -> u32 ----------------
__device__ __forceinline__ unsigned fmono(float f) {
  unsigned u = __float_as_uint(f);
  return (u & 0x80000000u) ? ~u : (u | 0x80000000u);
}

// ---------------- generic exact top-K select ----------------
struct TopkShared {
  int hist[4096];
  float bufv[4096];
  int bufi[4096];
  int misc[8];
};

// blockDim.x == 256. Produces >=K entries sorted (val desc, idx asc) in sh.bufv/bufi.
__device__ void topk_select(const float* __restrict__ row, int n, int K, TopkShared& sh) {
  const int tid = threadIdx.x;
  const int CAP = 4096;
  unsigned pfx = 0u;
  int hi_bits = 0;
  int above = 0;
  unsigned Tlo = 0u;

  for (int level = 0; level < 3; ++level) {
    const int w = (level == 2) ? 8 : 12;
    const int s = 32 - hi_bits - w;
    for (int i = tid; i < 4096; i += 256) sh.hist[i] = 0;
    __syncthreads();
    const unsigned hi_mask = hi_bits ? (0xFFFFFFFFu << (32 - hi_bits)) : 0u;
    for (int i = tid; i < n; i += 256) {
      unsigned u = fmono(row[i]);
      if ((u & hi_mask) == pfx)
        atomicAdd(&sh.hist[(u >> s) & ((1u << w) - 1u)], 1);
    }
    __syncthreads();
    const int nb = 1 << w;
    const int per = nb / 256;
    int csum = 0;
    for (int i = 0; i < per; ++i) csum += sh.hist[tid * per + i];
    sh.bufi[tid] = csum;
    __syncthreads();
    if (tid == 0) {
      int need = K - above;
      int cum = 0;
      int c = 255;
      for (; c > 0; --c) {
        if (cum + sh.bufi[c] >= need) break;
        cum += sh.bufi[c];
      }
      int b = (c + 1) * per - 1;
      for (; b > c * per; --b) {
        cum += sh.hist[b];
        if (cum >= need) break;
      }
      if (b == c * per) cum += sh.hist[b];  // may or may not reach need; b is floor
      sh.misc[0] = b;
      sh.misc[1] = cum;
      sh.misc[2] = sh.hist[b];
    }
    __syncthreads();
    const int bstar = sh.misc[0];
    const int cum = sh.misc[1];
    const int hb = sh.misc[2];
    const int sz = above + cum;
    __syncthreads();
    if (sz <= CAP || level == 2) {
      Tlo = pfx | ((unsigned)bstar << s);
      break;
    }
    above = above + cum - hb;
    pfx |= ((unsigned)bstar << s);
    hi_bits += w;
  }

  // collect
  if (tid == 0) sh.misc[3] = 0;
  __syncthreads();
  for (int i = tid; i < n; i += 256) {
    float f = row[i];
    if (fmono(f) >= Tlo) {
      int p = atomicAdd(&sh.misc[3], 1);
      if (p < CAP) { sh.bufv[p] = f; sh.bufi[p] = i; }
    }
  }
  __syncthreads();
  int cnt = sh.misc[3];
  if (cnt > CAP) cnt = CAP;
  int P = 1;
  while (P < cnt) P <<= 1;
  if (P < 2) P = 2;
  for (int i = cnt + tid; i < P; i += 256) { sh.bufv[i] = -INFINITY; sh.bufi[i] = 0x7FFFFFFF; }
  __syncthreads();
  // bitonic sort: val desc, idx asc
  for (int k2 = 2; k2 <= P; k2 <<= 1) {
    for (int j = k2 >> 1; j > 0; j >>= 1) {
      for (int i = tid; i < P; i += 256) {
        int l = i ^ j;
        if (l > i) {
          float vi = sh.bufv[i], vl = sh.bufv[l];
          int ii = sh.bufi[i], il = sh.bufi[l];
          bool iWorse = (vi < vl) || (vi == vl && ii > il);
          bool dirDesc = ((i & k2) == 0);
          if (dirDesc ? iWorse : !iWorse) {
            sh.bufv[i] = vl; sh.bufv[l] = vi;
            sh.bufi[i] = il; sh.bufi[l] = ii;
          }
        }
      }
      __syncthreads();
    }
  }
}

// ---------------- kernels ----------------
__global__ void normalize_kernel(const float* __restrict__ x, float* __restrict__ q) {
  int b = blockIdx.x;
  int t = threadIdx.x;  // 64
  float a = x[(size_t)b * D + t];
  float c = x[(size_t)b * D + t + 64];
  float ss = a * a + c * c;
  for (int o = 32; o; o >>= 1) ss += __shfl_xor(ss, o);
  float inv = 1.0f / fmaxf(sqrtf(ss), 1e-12f);
  q[(size_t)b * D + t] = a * inv;
  q[(size_t)b * D + t + 64] = c * inv;
}

__global__ void init_copy_kernel(const float* __restrict__ keys, const int* __restrict__ values,
                                 const float* __restrict__ age, float* __restrict__ out) {
  size_t stride = (size_t)gridDim.x * blockDim.x;
  size_t t0 = (size_t)blockIdx.x * blockDim.x + threadIdx.x;
  for (size_t i = t0; i < (size_t)M_SIZE * D; i += stride)
    out[OUT_KEYS + i] = keys[i];
  for (size_t i = t0; i < (size_t)M_SIZE; i += stride) {
    out[OUT_VALUES + i] = (float)values[i];
    out[OUT_AGE + i] = age[i] + 1.0f;
  }
}

#define BM 64
#define BG 64
#define BKK 64
__global__ __launch_bounds__(256) void gemm_kernel(const float* __restrict__ keys,
                                                   const float* __restrict__ q,
                                                   float* __restrict__ S, int Gc) {
  __shared__ float As[BM][BKK + 4];
  __shared__ float Bs[BG][BKK + 4];
  const int m0 = blockIdx.x * BM;
  const int g0 = blockIdx.y * BG;
  const int tid = threadIdx.x;
  const int tx = tid & 15;
  const int ty = tid >> 4;
  float acc[4][4];
#pragma unroll
  for (int j = 0; j < 4; j++)
#pragma unroll
    for (int i = 0; i < 4; i++) acc[j][i] = 0.f;

  for (int kk = 0; kk < D; kk += BKK) {
    for (int idx = tid; idx < BM * (BKK / 4); idx += 256) {
      int r = idx / (BKK / 4);
      int c4 = idx % (BKK / 4);
      float4 v = reinterpret_cast<const float4*>(keys + (size_t)(m0 + r) * D + kk)[c4];
      *reinterpret_cast<float4*>(&As[r][c4 * 4]) = v;
    }
    for (int idx = tid; idx < BG * (BKK / 4); idx += 256) {
      int r = idx / (BKK / 4);
      int c4 = idx % (BKK / 4);
      int g = g0 + r;
      float4 v = make_float4(0.f, 0.f, 0.f, 0.f);
      if (g < Gc) v = reinterpret_cast<const float4*>(q + (size_t)g * D + kk)[c4];
      *reinterpret_cast<float4*>(&Bs[r][c4 * 4]) = v;
    }
    __syncthreads();
#pragma unroll
    for (int k4 = 0; k4 < BKK; k4 += 4) {
      float4 av[4], bv[4];
#pragma unroll
      for (int i = 0; i < 4; i++) av[i] = *reinterpret_cast<float4*>(&As[i * 16 + tx][k4]);
#pragma unroll
      for (int j = 0; j < 4; j++) bv[j] = *reinterpret_cast<float4*>(&Bs[j * 16 + ty][k4]);
#pragma unroll
      for (int j = 0; j < 4; j++)
#pragma unroll
        for (int i = 0; i < 4; i++)
          acc[j][i] += av[i].x * bv[j].x + av[i].y * bv[j].y + av[i].z * bv[j].z + av[i].w * bv[j].w;
    }
    __syncthreads();
  }
#pragma unroll
  for (int j = 0; j < 4; j++) {
    int g = g0 + j * 16 + ty;
    if (g >= Gc) continue;
    float* dst = S + (size_t)g * M_SIZE + m0;
#pragma unroll
    for (int i = 0; i < 4; i++) dst[i * 16 + tx] = acc[j][i];
  }
}

__global__ __launch_bounds__(256) void topk_scores_kernel(
    const float* __restrict__ S, const int* __restrict__ values, const int* __restrict__ y,
    float* __restrict__ out, int* __restrict__ yidx, int* __restrict__ resf,
    int* __restrict__ anyinc, int g_start) {
  __shared__ TopkShared sh;
  __shared__ float wsum[4], wp[4], wn[4];
  const int bl = blockIdx.x;
  const int b = g_start + bl;
  const float* row = S + (size_t)bl * M_SIZE;
  topk_select(row, M_SIZE, K_TOP, sh);
  const int tid = threadIdx.x;
  float v = sh.bufv[tid];
  int idx = sh.bufi[tid];
  int val = values[idx];
  int yb = y[b];
  // softmax over the sorted top-K
  float mx = sh.bufv[0];
  float e = expf(TEMP * (v - mx));
  float se = e;
  for (int o = 32; o; o >>= 1) se += __shfl_xor(se, o);
  if ((tid & 63) == 0) wsum[tid >> 6] = se;
  __syncthreads();
  float tot = wsum[0] + wsum[1] + wsum[2] + wsum[3];
  out[OUT_SOFTMAX + (size_t)b * K_TOP + tid] = e / tot;
  // margin loss terms
  float m = (val == yb) ? 1.0f : 0.0f;
  float p = v * m;
  float ng = v * (1.0f - m);
  for (int o = 32; o; o >>= 1) {
    p = fmaxf(p, __shfl_xor(p, o));
    ng = fmaxf(ng, __shfl_xor(ng, o));
  }
  if ((tid & 63) == 0) { wp[tid >> 6] = p; wn[tid >> 6] = ng; }
  __syncthreads();
  if (tid == 0) {
    float pos = fmaxf(fmaxf(wp[0], wp[1]), fmaxf(wp[2], wp[3]));
    float neg = fmaxf(fmaxf(wn[0], wn[1]), fmaxf(wn[2], wn[3]));
    float lt = fmaxf(neg - pos + MARGIN, 0.0f) * (1.0f / B);
    atomicAdd(&out[OUT_LOSS], lt);
    int i0 = sh.bufi[0];
    int v0 = values[i0];
    out[OUT_YHAT + b] = (float)v0;
    yidx[b] = i0;
    int r = (v0 == yb) ? 1 : 0;
    resf[b] = r;
    if (!r) atomicOr(anyinc, 1);
  }
}

__global__ void winner_kernel(const int* __restrict__ yidx, int* __restrict__ winner) {
  __shared__ int sidx[B];
  int t = threadIdx.x;  // 1024
  sidx[t] = yidx[t];
  __syncthreads();
  int my = sidx[t];
  int w = 1;
  for (int b2 = t + 1; b2 < B; b2++)
    if (sidx[b2] == my) { w = 0; break; }
  winner[t] = w;
}

__global__ void cand_scatter_kernel(const float* __restrict__ keys, const float* __restrict__ q,
                                    const int* __restrict__ yidx, const int* __restrict__ resf,
                                    const int* __restrict__ winner, float* __restrict__ out) {
  int b = blockIdx.x;
  if (!winner[b] || !resf[b]) return;
  int t = threadIdx.x;  // 64
  int idx = yidx[b];
  float a = keys[(size_t)idx * D + t] + q[(size_t)b * D + t];
  float c = keys[(size_t)idx * D + t + 64] + q[(size_t)b * D + t + 64];
  float ss = a * a + c * c;
  for (int o = 32; o; o >>= 1) ss += __shfl_xor(ss, o);
  float inv = 1.0f / fmaxf(sqrtf(ss), 1e-12f);
  out[OUT_KEYS + (size_t)idx * D + t] = a * inv;
  out[OUT_KEYS + (size_t)idx * D + t + 64] = c * inv;
  if (t == 0) out[OUT_AGE + idx] = 0.0f;
}

__global__ void agenoise_kernel(const float* __restrict__ out, const float* __restrict__ noise,
                                float* __restrict__ an) {
  size_t stride = (size_t)gridDim.x * blockDim.x;
  for (size_t i = (size_t)blockIdx.x * blockDim.x + threadIdx.x; i < (size_t)M_SIZE; i += stride)
    an[i] = out[OUT_AGE + i] + noise[i];
}

__global__ __launch_bounds__(256) void topk_age_kernel(const float* __restrict__ an,
                                                       int* __restrict__ oldest) {
  __shared__ TopkShared sh;
  topk_select(an, M_SIZE, B, sh);
  for (int t = threadIdx.x; t < B; t += 256) oldest[t] = sh.bufi[t];
}

__global__ void scatter_old_kernel(const int* __restrict__ anyinc, const int* __restrict__ oldest,
                                   const float* __restrict__ q, const int* __restrict__ y,
                                   float* __restrict__ out) {
  if (*anyinc == 0) return;
  int j = blockIdx.x;
  int t = threadIdx.x;  // 64
  int o = oldest[j];
  out[OUT_KEYS + (size_t)o * D + t] = q[(size_t)j * D + t];
  out[OUT_KEYS + (size_t)o * D + t + 64] = q[(size_t)j * D + t + 64];
  if (t == 0) {
    out[OUT_VALUES + o] = (float)y[j];
    out[OUT_AGE + o] = 0.0f;
  }
}

extern "C" void kernel_launch(void* const* d_in, const int* in_sizes, int n_in,
                              void* d_out, int out_size, void* d_ws, size_t ws_size,
                              hipStream_t stream) {
  const float* x = (const float*)d_in[0];
  const int* y = (const int*)d_in[1];
  const float* keys = (const float*)d_in[2];
  const int* values = (const int*)d_in[3];
  const float* age = (const float*)d_in[4];
  const float* noise = (const float*)d_in[5];
  float* out = (float*)d_out;

  float* ws = (float*)d_ws;
  float* q = ws;                          // 131072 floats
  int* yidx = (int*)(ws + 131072);        // 1024
  int* resf = (int*)(ws + 132096);        // 1024
  int* winner = (int*)(ws + 133120);      // 1024
  int* anyinc = (int*)(ws + 134144);      // 1
  int* oldest = (int*)(ws + 134400);      // 1024
  float* an = ws + 135424;                // M floats -> ends at 397568
  float* S = ws + 524288;                 // scores chunk buffer @ 2MB

  size_t avail = (ws_size > (size_t)(2u << 20)) ? (ws_size - (size_t)(2u << 20)) : 0;
  int G = (int)(avail / ((size_t)M_SIZE * 4));
  if (G > B) G = B;
  if (G < 1) G = 1;

  hipMemsetAsync(out + OUT_LOSS, 0, sizeof(float), stream);
  hipMemsetAsync(anyinc, 0, sizeof(int), stream);

  normalize_kernel<<<B, 64, 0, stream>>>(x, q);
  init_copy_kernel<<<2048, 256, 0, stream>>>(keys, values, age, out);

  for (int g0 = 0; g0 < B; g0 += G) {
    int Gc = (B - g0 < G) ? (B - g0) : G;
    dim3 grid(M_SIZE / BM, (Gc + BG - 1) / BG);
    gemm_kernel<<<grid, 256, 0, stream>>>(keys, q + (size_t)g0 * D, S, Gc);
    topk_scores_kernel<<<Gc, 256, 0, stream>>>(S, values, y, out, yidx, resf, anyinc, g0);
  }

  winner_kernel<<<1, 1024, 0, stream>>>(yidx, winner);
  cand_scatter_kernel<<<B, 64, 0, stream>>>(keys, q, yidx, resf, winner, out);
  agenoise_kernel<<<512, 256, 0, stream>>>(out, noise, an);
  topk_age_kernel<<<1, 256, 0, stream>>>(an, oldest);
  scatter_old_kernel<<<B, 64, 0, stream>>>(anyinc, oldest, q, y, out);
}

// Round 6
// 4531.052 us; speedup vs baseline: 1.2961x; 1.2961x over previous
//
#include <hip/hip_runtime.h>
#include <hip/hip_bf16.h>
#include <math.h>
#include <stdint.h>

#define M_SIZE 262144
#define D 128
#define B 1024
#define K_TOP 256
#define MARGIN 0.1f
#define TEMP 1.0f   // max(1, log(0.2*256)/40) = 1.0
#define T0_SCORE 0.2f
#define T0_AGE 8.9f
#define CAP 4096

typedef unsigned int u32;
typedef unsigned long long u64;
typedef __attribute__((ext_vector_type(8))) short bf16x8;
typedef __attribute__((ext_vector_type(16))) float f32x16;

// d_out layout (float32, return order)
#define OUT_YHAT 0
#define OUT_SOFTMAX (B)
#define OUT_LOSS (B + B * K_TOP)                  // 263168
#define OUT_KEYS (OUT_LOSS + 1)                   // 263169
#define OUT_VALUES (OUT_KEYS + (size_t)M_SIZE * D)
#define OUT_AGE (OUT_VALUES + M_SIZE)

// ws layout (float units)
#define WS_Q        0
#define WS_YIDX     131072
#define WS_RESF     132096
#define WS_WINNER   133120
#define WS_ANYINC   134144
#define WS_OLDEST   134400
#define WS_CNTS     135424
#define WS_CNTAGE   136448
#define WS_AN       137216
#define WS_QHI      399360
#define WS_QLO      464896
#define WS_KHI      530432
#define WS_KLO      17307648
#define WS_CANDS    34084864
#define WS_CANDAGE  42473472

__device__ __forceinline__ unsigned fmono(float f) {
  unsigned u = __float_as_uint(f);
  return (u & 0x80000000u) ? ~u : (u | 0x80000000u);
}
__device__ __forceinline__ float unmono(u32 u) {
  u32 b = (u & 0x80000000u) ? (u & 0x7FFFFFFFu) : ~u;
  return __uint_as_float(b);
}
__device__ __forceinline__ ushort bf16_rn(float f) {
  u32 u = __float_as_uint(f);
  u32 r = (u + 0x7FFFu + ((u >> 16) & 1u)) >> 16;
  return (ushort)r;
}
__device__ __forceinline__ float bf16_to_f(ushort h) {
  return __uint_as_float(((u32)h) << 16);
}
__device__ __forceinline__ void gload16(const void* g, void* l) {
  __builtin_amdgcn_global_load_lds(
      (const __attribute__((address_space(1))) unsigned int*)g,
      (__attribute__((address_space(3))) unsigned int*)l, 16, 0, 0);
}
__device__ __forceinline__ u64 packvi(float v, int i) {
  return ((u64)fmono(v) << 32) | (u32)(~(u32)i);
}

// ---------------- generic exact top-K (fallback path; functor-based) ----------------
struct TS {
  int hist[4096];
  float bufv[4096];
  int bufi[4096];
  int misc[8];
};

template <typename F>
__device__ void topk_select_f(F score, int n, int K, TS& sh) {
  const int tid = threadIdx.x;
  unsigned pfx = 0u;
  int hi_bits = 0;
  int above = 0;
  unsigned Tlo = 0u;

  for (int level = 0; level < 3; ++level) {
    const int w = (level == 2) ? 8 : 12;
    const int s = 32 - hi_bits - w;
    for (int i = tid; i < 4096; i += 256) sh.hist[i] = 0;
    __syncthreads();
    const unsigned hi_mask = hi_bits ? (0xFFFFFFFFu << (32 - hi_bits)) : 0u;
    for (int i = tid; i < n; i += 256) {
      unsigned u = fmono(score(i));
      if ((u & hi_mask) == pfx)
        atomicAdd(&sh.hist[(u >> s) & ((1u << w) - 1u)], 1);
    }
    __syncthreads();
    const int nb = 1 << w;
    const int per = nb / 256;
    int csum = 0;
    for (int i = 0; i < per; ++i) csum += sh.hist[tid * per + i];
    sh.bufi[tid] = csum;
    __syncthreads();
    if (tid == 0) {
      int need = K - above;
      int cum = 0;
      int c = 255;
      for (; c > 0; --c) {
        if (cum + sh.bufi[c] >= need) break;
        cum += sh.bufi[c];
      }
      int b = (c + 1) * per - 1;
      for (; b > c * per; --b) {
        cum += sh.hist[b];
        if (cum >= need) break;
      }
      if (b == c * per) cum += sh.hist[b];
      sh.misc[0] = b;
      sh.misc[1] = cum;
      sh.misc[2] = sh.hist[b];
    }
    __syncthreads();
    const int bstar = sh.misc[0];
    const int cum = sh.misc[1];
    const int hb = sh.misc[2];
    const int sz = above + cum;
    __syncthreads();
    if (sz <= CAP || level == 2) {
      Tlo = pfx | ((unsigned)bstar << s);
      break;
    }
    above = above + cum - hb;
    pfx |= ((unsigned)bstar << s);
    hi_bits += w;
  }

  if (tid == 0) sh.misc[3] = 0;
  __syncthreads();
  for (int i = tid; i < n; i += 256) {
    float f = score(i);
    if (fmono(f) >= Tlo) {
      int p = atomicAdd(&sh.misc[3], 1);
      if (p < CAP) { sh.bufv[p] = f; sh.bufi[p] = i; }
    }
  }
  __syncthreads();
  int cnt = sh.misc[3];
  if (cnt > CAP) cnt = CAP;
  int P = 1;
  while (P < cnt) P <<= 1;
  if (P < 2) P = 2;
  for (int i = cnt + tid; i < P; i += 256) { sh.bufv[i] = -INFINITY; sh.bufi[i] = 0x7FFFFFFF; }
  __syncthreads();
  for (int k2 = 2; k2 <= P; k2 <<= 1) {
    for (int j = k2 >> 1; j > 0; j >>= 1) {
      for (int i = tid; i < P; i += 256) {
        int l = i ^ j;
        if (l > i) {
          float vi = sh.bufv[i], vl = sh.bufv[l];
          int ii = sh.bufi[i], il = sh.bufi[l];
          bool iWorse = (vi < vl) || (vi == vl && ii > il);
          bool dirDesc = ((i & k2) == 0);
          if (dirDesc ? iWorse : !iWorse) {
            sh.bufv[i] = vl; sh.bufv[l] = vi;
            sh.bufi[i] = il; sh.bufi[l] = ii;
          }
        }
      }
      __syncthreads();
    }
  }
}

struct AnScore {
  const float* an;
  __device__ float operator()(int i) const { return an[i]; }
};
struct DotScore {
  const float* qr;     // shared, 128 f32
  const float* keys;   // global
  __device__ float operator()(int m) const {
    const float4* kr = (const float4*)(keys + (size_t)m * D);
    const float4* qv = (const float4*)qr;
    float s[4] = {0.f, 0.f, 0.f, 0.f};
#pragma unroll
    for (int c = 0; c < 32; ++c) {
      float4 kv = kr[c];
      float4 qq = qv[c];
      s[c & 3] += kv.x * qq.x + kv.y * qq.y + kv.z * qq.z + kv.w * qq.w;
    }
    return (s[0] + s[1]) + (s[2] + s[3]);
  }
};

__device__ void bitonic4096_desc(u64* sk, int tid) {
  for (int k2 = 2; k2 <= 4096; k2 <<= 1) {
    for (int j = k2 >> 1; j > 0; j >>= 1) {
      for (int i = tid; i < 4096; i += 256) {
        int l = i ^ j;
        if (l > i) {
          u64 a = sk[i], b = sk[l];
          bool dirDesc = ((i & k2) == 0);
          if (dirDesc ? (a < b) : (a > b)) { sk[i] = b; sk[l] = a; }
        }
      }
      __syncthreads();
    }
  }
}

// ---------------- kernels ----------------
__global__ void normalize_prep(const float* __restrict__ x, float* __restrict__ q,
                               ushort* __restrict__ qhi, ushort* __restrict__ qlo) {
  int b = blockIdx.x;
  int t = threadIdx.x;  // 64
  float a = x[(size_t)b * D + t];
  float c = x[(size_t)b * D + t + 64];
  float ss = a * a + c * c;
  for (int o = 32; o; o >>= 1) ss += __shfl_xor(ss, o);
  float inv = 1.0f / fmaxf(sqrtf(ss), 1e-12f);
  a *= inv; c *= inv;
  q[(size_t)b * D + t] = a;
  q[(size_t)b * D + t + 64] = c;
#pragma unroll
  for (int h = 0; h < 2; ++h) {
    int k = t + h * 64;
    float v = h ? c : a;
    int chunk = k >> 6, cc = (k >> 3) & 7, j = k & 7;
    int cd = cc ^ (b & 7);
    int pos = b * 128 + chunk * 64 + cd * 8 + j;
    ushort hb = bf16_rn(v);
    qhi[pos] = hb;
    qlo[pos] = bf16_rn(v - bf16_to_f(hb));
  }
}

// fused: out<-keys copy, keys hi/lo swizzled bf16 prep, values/age init
__global__ void prep_init(const float* __restrict__ keys, const int* __restrict__ values,
                          const float* __restrict__ age, float* __restrict__ out,
                          ushort* __restrict__ khi, ushort* __restrict__ klo) {
  size_t stride = (size_t)gridDim.x * blockDim.x;
  size_t t0 = (size_t)blockIdx.x * blockDim.x + threadIdx.x;
  size_t nslots = (size_t)M_SIZE * 16;
  for (size_t s = t0; s < nslots; s += stride) {
    int m = (int)(s >> 4);
    int sc = (int)(s & 15);
    int chunk = sc >> 3, c = sc & 7;
    int csrc = c ^ (m & 7);
    size_t src = (size_t)m * 128 + chunk * 64 + csrc * 8;
    float4 v0 = *(const float4*)(keys + src);
    float4 v1 = *(const float4*)(keys + src + 4);
    *(float4*)(out + OUT_KEYS + src) = v0;
    *(float4*)(out + OUT_KEYS + src + 4) = v1;
    size_t dst = (size_t)m * 128 + chunk * 64 + c * 8;
    float vv[8] = {v0.x, v0.y, v0.z, v0.w, v1.x, v1.y, v1.z, v1.w};
    ushort h[8], l[8];
#pragma unroll
    for (int e = 0; e < 8; ++e) {
      h[e] = bf16_rn(vv[e]);
      l[e] = bf16_rn(vv[e] - bf16_to_f(h[e]));
    }
    *(uint4*)(khi + dst) = *(uint4*)h;
    *(uint4*)(klo + dst) = *(uint4*)l;
  }
  for (size_t i = t0; i < (size_t)M_SIZE; i += stride) {
    out[OUT_VALUES + i] = (float)values[i];
    out[OUT_AGE + i] = age[i] + 1.0f;
  }
}

// 3-pass split-bf16 MFMA GEMM, fused candidate collection (no score matrix).
// block: 128 keys x 128 queries, 4 waves (2x2), wave tile 64x64 via 2x2 mfma_f32_32x32x16_bf16.
__global__ __launch_bounds__(256, 2) void gemm_topk(
    const ushort* __restrict__ khi, const ushort* __restrict__ klo,
    const ushort* __restrict__ qhi, const ushort* __restrict__ qlo,
    u64* __restrict__ cand, int* __restrict__ cnts) {
  __shared__ __align__(16) char lds[65536];
  char* KH = lds;
  char* KL = lds + 16384;
  char* QH = lds + 32768;
  char* QL = lds + 49152;
  const int m0 = blockIdx.x * 128;
  const int g0 = blockIdx.y * 128;
  const int tid = threadIdx.x;
  const int w = tid >> 6;
  const int lane = tid & 63;
  const int wm = w & 1;
  const int wq = w >> 1;

  f32x16 acc[2][2];
#pragma unroll
  for (int i = 0; i < 2; ++i)
#pragma unroll
    for (int j = 0; j < 2; ++j)
#pragma unroll
      for (int e = 0; e < 16; ++e) acc[i][j][e] = 0.f;

  for (int kc = 0; kc < 2; ++kc) {
    if (kc) __syncthreads();
    // stage 4 planes of [128 rows][64 bf16] via global_load_lds (pre-swizzled source)
#pragma unroll
    for (int it = 0; it < 4; ++it) {
      int blk = w * 4 + it;
      int rr = blk * 8 + (lane >> 3);
      int cc = lane & 7;
      size_t kidx = (size_t)(m0 + rr) * 128 + kc * 64 + cc * 8;
      size_t qidx = (size_t)(g0 + rr) * 128 + kc * 64 + cc * 8;
      int lo = blk * 1024;
      gload16(khi + kidx, KH + lo);
      gload16(klo + kidx, KL + lo);
      gload16(qhi + qidx, QH + lo);
      gload16(qlo + qidx, QL + lo);
    }
    __syncthreads();
#pragma unroll
    for (int ks = 0; ks < 4; ++ks) {
      bf16x8 aH[2], aL[2], bH[2], bL[2];
      int kb = ks * 32 + ((lane >> 5) << 4);
#pragma unroll
      for (int i = 0; i < 2; ++i) {
        int row = wm * 64 + i * 32 + (lane & 31);
        int off = row * 128 + (kb ^ ((row & 7) << 4));
        aH[i] = *(const bf16x8*)(KH + off);
        aL[i] = *(const bf16x8*)(KL + off);
      }
#pragma unroll
      for (int j = 0; j < 2; ++j) {
        int row = wq * 64 + j * 32 + (lane & 31);
        int off = row * 128 + (kb ^ ((row & 7) << 4));
        bH[j] = *(const bf16x8*)(QH + off);
        bL[j] = *(const bf16x8*)(QL + off);
      }
#pragma unroll
      for (int i = 0; i < 2; ++i)
#pragma unroll
        for (int j = 0; j < 2; ++j) {
          acc[i][j] = __builtin_amdgcn_mfma_f32_32x32x16_bf16(aH[i], bH[j], acc[i][j], 0, 0, 0);
          acc[i][j] = __builtin_amdgcn_mfma_f32_32x32x16_bf16(aH[i], bL[j], acc[i][j], 0, 0, 0);
          acc[i][j] = __builtin_amdgcn_mfma_f32_32x32x16_bf16(aL[i], bH[j], acc[i][j], 0, 0, 0);
        }
    }
  }
  // epilogue: push candidates > T0. C/D: col(query)=lane&31, row(key)=(reg&3)+8*(reg>>2)+4*(lane>>5)
#pragma unroll
  for (int i = 0; i < 2; ++i)
#pragma unroll
    for (int j = 0; j < 2; ++j) {
      int g = g0 + wq * 64 + j * 32 + (lane & 31);
      int mbase = m0 + wm * 64 + i * 32 + 4 * (lane >> 5);
#pragma unroll
      for (int r16 = 0; r16 < 16; ++r16) {
        float v = acc[i][j][r16];
        if (v > T0_SCORE) {
          int m = mbase + (r16 & 3) + 8 * (r16 >> 2);
          int slot = atomicAdd(&cnts[g], 1);
          if (slot < CAP) cand[(size_t)g * CAP + slot] = packvi(v, m);
        }
      }
    }
}

struct SelShared {
  union {
    u64 sk[CAP];
    TS ts;
  } u;
  alignas(16) float qrow[D];
  float red[12];
  float ex8[8];
  int exi8[8];
  int besti;
};

__global__ __launch_bounds__(256) void select_scores(
    const u64* __restrict__ cand, const int* __restrict__ cnts,
    const float* __restrict__ q, const float* __restrict__ keys,
    const int* __restrict__ values, const int* __restrict__ y,
    float* __restrict__ out, int* __restrict__ yidx, int* __restrict__ resf,
    int* __restrict__ anyinc) {
  __shared__ SelShared sh;
  const int b = blockIdx.x;
  const int tid = threadIdx.x;
  const int n = cnts[b];
  const bool good = (n >= K_TOP && n <= CAP);

  for (int t = tid; t < D; t += 256) sh.qrow[t] = q[(size_t)b * D + t];
  __syncthreads();

  float v;
  int idx;
  float mx;
  if (good) {
    for (int t = tid; t < n; t += 256) sh.u.sk[t] = cand[(size_t)b * CAP + t];
    for (int t = n + tid; t < CAP; t += 256) sh.u.sk[t] = 0ull;
    __syncthreads();
    bitonic4096_desc(sh.u.sk, tid);
    u64 kk = sh.u.sk[tid];
    v = unmono((u32)(kk >> 32));
    idx = (int)(~(u32)kk);
    mx = unmono((u32)(sh.u.sk[0] >> 32));
    // exact f32 recompute of top-8 -> argmax robustness
    if (tid < 8) {
      int m = (int)(~(u32)sh.u.sk[tid]);
      DotScore ds{sh.qrow, keys};
      sh.ex8[tid] = ds(m);
      sh.exi8[tid] = m;
    }
    __syncthreads();
    if (tid == 0) {
      float bs = sh.ex8[0];
      int bm = sh.exi8[0];
      for (int t = 1; t < 8; ++t) {
        if (sh.ex8[t] > bs || (sh.ex8[t] == bs && sh.exi8[t] < bm)) {
          bs = sh.ex8[t]; bm = sh.exi8[t];
        }
      }
      sh.besti = bm;
    }
  } else {
    // fallback: exact full recompute selection (never expected to trigger)
    DotScore ds{sh.qrow, keys};
    topk_select_f(ds, M_SIZE, K_TOP, sh.u.ts);
    v = sh.u.ts.bufv[tid];
    idx = sh.u.ts.bufi[tid];
    mx = sh.u.ts.bufv[0];
    if (tid == 0) sh.besti = sh.u.ts.bufi[0];
  }
  __syncthreads();

  // softmax over sorted top-K
  float e = expf(TEMP * (v - mx));
  float se = e;
  for (int o = 32; o; o >>= 1) se += __shfl_xor(se, o);
  if ((tid & 63) == 0) sh.red[tid >> 6] = se;
  __syncthreads();
  float tot = sh.red[0] + sh.red[1] + sh.red[2] + sh.red[3];
  out[OUT_SOFTMAX + (size_t)b * K_TOP + tid] = e / tot;

  int val = values[idx];
  int yb = y[b];
  float mval = (val == yb) ? 1.0f : 0.0f;
  float p = v * mval;
  float ng = v * (1.0f - mval);
  for (int o = 32; o; o >>= 1) {
    p = fmaxf(p, __shfl_xor(p, o));
    ng = fmaxf(ng, __shfl_xor(ng, o));
  }
  if ((tid & 63) == 0) { sh.red[4 + (tid >> 6)] = p; sh.red[8 + (tid >> 6)] = ng; }
  __syncthreads();
  if (tid == 0) {
    float pos = fmaxf(fmaxf(sh.red[4], sh.red[5]), fmaxf(sh.red[6], sh.red[7]));
    float neg = fmaxf(fmaxf(sh.red[8], sh.red[9]), fmaxf(sh.red[10], sh.red[11]));
    float lt = fmaxf(neg - pos + MARGIN, 0.0f) * (1.0f / B);
    atomicAdd(&out[OUT_LOSS], lt);
    int i0 = sh.besti;
    int v0 = values[i0];
    out[OUT_YHAT + b] = (float)v0;
    yidx[b] = i0;
    int r = (v0 == yb) ? 1 : 0;
    resf[b] = r;
    if (!r) atomicOr(anyinc, 1);
  }
}

__global__ void winner_kernel(const int* __restrict__ yidx, int* __restrict__ winner) {
  __shared__ int sidx[B];
  int t = threadIdx.x;  // 1024
  sidx[t] = yidx[t];
  __syncthreads();
  int my = sidx[t];
  int w = 1;
  for (int b2 = t + 1; b2 < B; b2++)
    if (sidx[b2] == my) { w = 0; break; }
  winner[t] = w;
}

__global__ void cand_scatter_kernel(const float* __restrict__ keys, const float* __restrict__ q,
                                    const int* __restrict__ yidx, const int* __restrict__ resf,
                                    const int* __restrict__ winner, float* __restrict__ out) {
  int b = blockIdx.x;
  if (!winner[b] || !resf[b]) return;
  int t = threadIdx.x;  // 64
  int idx = yidx[b];
  float a = keys[(size_t)idx * D + t] + q[(size_t)b * D + t];
  float c = keys[(size_t)idx * D + t + 64] + q[(size_t)b * D + t + 64];
  float ss = a * a + c * c;
  for (int o = 32; o; o >>= 1) ss += __shfl_xor(ss, o);
  float inv = 1.0f / fmaxf(sqrtf(ss), 1e-12f);
  out[OUT_KEYS + (size_t)idx * D + t] = a * inv;
  out[OUT_KEYS + (size_t)idx * D + t + 64] = c * inv;
  if (t == 0) out[OUT_AGE + idx] = 0.0f;
}

__global__ void agenoise_kernel(const float* __restrict__ out, const float* __restrict__ noise,
                                float* __restrict__ an) {
  size_t stride = (size_t)gridDim.x * blockDim.x;
  for (size_t i = (size_t)blockIdx.x * blockDim.x + threadIdx.x; i < (size_t)M_SIZE; i += stride)
    an[i] = out[OUT_AGE + i] + noise[i];
}

__global__ void age_collect(const float* __restrict__ an, u64* __restrict__ cand,
                            int* __restrict__ cnt) {
  size_t stride = (size_t)gridDim.x * blockDim.x;
  for (size_t i = (size_t)blockIdx.x * blockDim.x + threadIdx.x; i < (size_t)M_SIZE; i += stride) {
    float v = an[i];
    if (v > T0_AGE) {
      int slot = atomicAdd(cnt, 1);
      if (slot < CAP) cand[slot] = packvi(v, (int)i);
    }
  }
}

struct AgeShared {
  union {
    u64 sk[CAP];
    TS ts;
  } u;
};

__global__ __launch_bounds__(256) void age_select(const float* __restrict__ an,
                                                  const u64* __restrict__ cand,
                                                  const int* __restrict__ cnt,
                                                  int* __restrict__ oldest) {
  __shared__ AgeShared sh;
  const int tid = threadIdx.x;
  const int n = *cnt;
  if (n >= B && n <= CAP) {
    for (int t = tid; t < n; t += 256) sh.u.sk[t] = cand[t];
    for (int t = n + tid; t < CAP; t += 256) sh.u.sk[t] = 0ull;
    __syncthreads();
    bitonic4096_desc(sh.u.sk, tid);
    for (int t = tid; t < B; t += 256) oldest[t] = (int)(~(u32)sh.u.sk[t]);
  } else {
    AnScore as{an};
    topk_select_f(as, M_SIZE, B, sh.u.ts);
    for (int t = tid; t < B; t += 256) oldest[t] = sh.u.ts.bufi[t];
  }
}

__global__ void scatter_old_kernel(const int* __restrict__ anyinc, const int* __restrict__ oldest,
                                   const float* __restrict__ q, const int* __restrict__ y,
                                   float* __restrict__ out) {
  if (*anyinc == 0) return;
  int j = blockIdx.x;
  int t = threadIdx.x;  // 64
  int o = oldest[j];
  out[OUT_KEYS + (size_t)o * D + t] = q[(size_t)j * D + t];
  out[OUT_KEYS + (size_t)o * D + t + 64] = q[(size_t)j * D + t + 64];
  if (t == 0) {
    out[OUT_VALUES + o] = (float)y[j];
    out[OUT_AGE + o] = 0.0f;
  }
}

extern "C" void kernel_launch(void* const* d_in, const int* in_sizes, int n_in,
                              void* d_out, int out_size, void* d_ws, size_t ws_size,
                              hipStream_t stream) {
  const float* x = (const float*)d_in[0];
  const int* y = (const int*)d_in[1];
  const float* keys = (const float*)d_in[2];
  const int* values = (const int*)d_in[3];
  const float* age = (const float*)d_in[4];
  const float* noise = (const float*)d_in[5];
  float* out = (float*)d_out;

  float* ws = (float*)d_ws;
  float* q = ws + WS_Q;
  int* yidx = (int*)(ws + WS_YIDX);
  int* resf = (int*)(ws + WS_RESF);
  int* winner = (int*)(ws + WS_WINNER);
  int* anyinc = (int*)(ws + WS_ANYINC);
  int* oldest = (int*)(ws + WS_OLDEST);
  int* cnts = (int*)(ws + WS_CNTS);
  int* cntage = (int*)(ws + WS_CNTAGE);
  float* an = ws + WS_AN;
  ushort* qhi = (ushort*)(ws + WS_QHI);
  ushort* qlo = (ushort*)(ws + WS_QLO);
  ushort* khi = (ushort*)(ws + WS_KHI);
  ushort* klo = (ushort*)(ws + WS_KLO);
  u64* cands = (u64*)(ws + WS_CANDS);
  u64* candage = (u64*)(ws + WS_CANDAGE);

  hipMemsetAsync(out + OUT_LOSS, 0, sizeof(float), stream);
  hipMemsetAsync(anyinc, 0, sizeof(int), stream);
  hipMemsetAsync(cnts, 0, B * sizeof(int), stream);
  hipMemsetAsync(cntage, 0, sizeof(int), stream);

  normalize_prep<<<B, 64, 0, stream>>>(x, q, qhi, qlo);
  prep_init<<<4096, 256, 0, stream>>>(keys, values, age, out, khi, klo);
  gemm_topk<<<dim3(M_SIZE / 128, B / 128), 256, 0, stream>>>(khi, klo, qhi, qlo, cands, cnts);
  select_scores<<<B, 256, 0, stream>>>(cands, cnts, q, keys, values, y, out, yidx, resf, anyinc);
  winner_kernel<<<1, 1024, 0, stream>>>(yidx, winner);
  cand_scatter_kernel<<<B, 64, 0, stream>>>(keys, q, yidx, resf, winner, out);
  agenoise_kernel<<<512, 256, 0, stream>>>(out, noise, an);
  age_collect<<<256, 256, 0, stream>>>(an, candage, cntage);
  age_select<<<1, 256, 0, stream>>>(an, candage, cntage, oldest);
  scatter_old_kernel<<<B, 64, 0, stream>>>(anyinc, oldest, q, y, out);
}

// Round 7
// 1209.769 us; speedup vs baseline: 4.8544x; 3.7454x over previous
//
#include <hip/hip_runtime.h>
#include <hip/hip_bf16.h>
#include <math.h>
#include <stdint.h>

#define M_SIZE 262144
#define D 128
#define B 1024
#define K_TOP 256
#define MARGIN 0.1f
#define TEMP 1.0f   // max(1, log(0.2*256)/40) = 1.0
#define T0_SCORE 0.2f
#define T0_AGE 8.9f
#define CAP 4096

typedef unsigned int u32;
typedef unsigned long long u64;
typedef __attribute__((ext_vector_type(8))) short bf16x8;
typedef __attribute__((ext_vector_type(16))) float f32x16;

// d_out layout (float32, return order)
#define OUT_YHAT 0
#define OUT_SOFTMAX (B)
#define OUT_LOSS (B + B * K_TOP)                  // 263168
#define OUT_KEYS (OUT_LOSS + 1)                   // 263169
#define OUT_VALUES (OUT_KEYS + (size_t)M_SIZE * D)
#define OUT_AGE (OUT_VALUES + M_SIZE)

// ws layout (float units)
#define WS_Q        0
#define WS_YIDX     131072
#define WS_RESF     132096
#define WS_WINNER   133120
#define WS_ANYINC   134144
#define WS_OLDEST   134400
#define WS_CNTS     135424
#define WS_CNTAGE   136448
#define WS_AN       137216
#define WS_QHI      399360
#define WS_QLO      464896
#define WS_KHI      530432
#define WS_KLO      17307648
#define WS_CANDS    34084864
#define WS_CANDAGE  42473472

__device__ __forceinline__ unsigned fmono(float f) {
  unsigned u = __float_as_uint(f);
  return (u & 0x80000000u) ? ~u : (u | 0x80000000u);
}
__device__ __forceinline__ float unmono(u32 u) {
  u32 b = (u & 0x80000000u) ? (u & 0x7FFFFFFFu) : ~u;
  return __uint_as_float(b);
}
__device__ __forceinline__ ushort bf16_rn(float f) {
  u32 u = __float_as_uint(f);
  u32 r = (u + 0x7FFFu + ((u >> 16) & 1u)) >> 16;
  return (ushort)r;
}
__device__ __forceinline__ float bf16_to_f(ushort h) {
  return __uint_as_float(((u32)h) << 16);
}
__device__ __forceinline__ void gload16(const void* g, void* l) {
  __builtin_amdgcn_global_load_lds(
      (const __attribute__((address_space(1))) unsigned int*)g,
      (__attribute__((address_space(3))) unsigned int*)l, 16, 0, 0);
}
__device__ __forceinline__ u64 packvi(float v, int i) {
  return ((u64)fmono(v) << 32) | (u32)(~(u32)i);
}

// ---------------- generic exact top-K (fallback path; functor-based) ----------------
struct TS {
  int hist[4096];
  float bufv[4096];
  int bufi[4096];
  int misc[8];
};

template <typename F>
__device__ void topk_select_f(F score, int n, int K, TS& sh) {
  const int tid = threadIdx.x;
  unsigned pfx = 0u;
  int hi_bits = 0;
  int above = 0;
  unsigned Tlo = 0u;

  for (int level = 0; level < 3; ++level) {
    const int w = (level == 2) ? 8 : 12;
    const int s = 32 - hi_bits - w;
    for (int i = tid; i < 4096; i += 256) sh.hist[i] = 0;
    __syncthreads();
    const unsigned hi_mask = hi_bits ? (0xFFFFFFFFu << (32 - hi_bits)) : 0u;
    for (int i = tid; i < n; i += 256) {
      unsigned u = fmono(score(i));
      if ((u & hi_mask) == pfx)
        atomicAdd(&sh.hist[(u >> s) & ((1u << w) - 1u)], 1);
    }
    __syncthreads();
    const int nb = 1 << w;
    const int per = nb / 256;
    int csum = 0;
    for (int i = 0; i < per; ++i) csum += sh.hist[tid * per + i];
    sh.bufi[tid] = csum;
    __syncthreads();
    if (tid == 0) {
      int need = K - above;
      int cum = 0;
      int c = 255;
      for (; c > 0; --c) {
        if (cum + sh.bufi[c] >= need) break;
        cum += sh.bufi[c];
      }
      int b = (c + 1) * per - 1;
      for (; b > c * per; --b) {
        cum += sh.hist[b];
        if (cum >= need) break;
      }
      if (b == c * per) cum += sh.hist[b];
      sh.misc[0] = b;
      sh.misc[1] = cum;
      sh.misc[2] = sh.hist[b];
    }
    __syncthreads();
    const int bstar = sh.misc[0];
    const int cum = sh.misc[1];
    const int hb = sh.misc[2];
    const int sz = above + cum;
    __syncthreads();
    if (sz <= CAP || level == 2) {
      Tlo = pfx | ((unsigned)bstar << s);
      break;
    }
    above = above + cum - hb;
    pfx |= ((unsigned)bstar << s);
    hi_bits += w;
  }

  if (tid == 0) sh.misc[3] = 0;
  __syncthreads();
  for (int i = tid; i < n; i += 256) {
    float f = score(i);
    if (fmono(f) >= Tlo) {
      int p = atomicAdd(&sh.misc[3], 1);
      if (p < CAP) { sh.bufv[p] = f; sh.bufi[p] = i; }
    }
  }
  __syncthreads();
  int cnt = sh.misc[3];
  if (cnt > CAP) cnt = CAP;
  int P = 1;
  while (P < cnt) P <<= 1;
  if (P < 2) P = 2;
  for (int i = cnt + tid; i < P; i += 256) { sh.bufv[i] = -INFINITY; sh.bufi[i] = 0x7FFFFFFF; }
  __syncthreads();
  for (int k2 = 2; k2 <= P; k2 <<= 1) {
    for (int j = k2 >> 1; j > 0; j >>= 1) {
      for (int i = tid; i < P; i += 256) {
        int l = i ^ j;
        if (l > i) {
          float vi = sh.bufv[i], vl = sh.bufv[l];
          int ii = sh.bufi[i], il = sh.bufi[l];
          bool iWorse = (vi < vl) || (vi == vl && ii > il);
          bool dirDesc = ((i & k2) == 0);
          if (dirDesc ? iWorse : !iWorse) {
            sh.bufv[i] = vl; sh.bufv[l] = vi;
            sh.bufi[i] = il; sh.bufi[l] = ii;
          }
        }
      }
      __syncthreads();
    }
  }
}

struct AnScore {
  const float* an;
  __device__ float operator()(int i) const { return an[i]; }
};
struct DotScore {
  const float* qr;     // shared, 128 f32
  const float* keys;   // global
  __device__ float operator()(int m) const {
    const float4* kr = (const float4*)(keys + (size_t)m * D);
    const float4* qv = (const float4*)qr;
    float s[4] = {0.f, 0.f, 0.f, 0.f};
#pragma unroll
    for (int c = 0; c < 32; ++c) {
      float4 kv = kr[c];
      float4 qq = qv[c];
      s[c & 3] += kv.x * qq.x + kv.y * qq.y + kv.z * qq.z + kv.w * qq.w;
    }
    return (s[0] + s[1]) + (s[2] + s[3]);
  }
};

__device__ void bitonic4096_desc(u64* sk, int tid) {
  for (int k2 = 2; k2 <= 4096; k2 <<= 1) {
    for (int j = k2 >> 1; j > 0; j >>= 1) {
      for (int i = tid; i < 4096; i += 256) {
        int l = i ^ j;
        if (l > i) {
          u64 a = sk[i], b = sk[l];
          bool dirDesc = ((i & k2) == 0);
          if (dirDesc ? (a < b) : (a > b)) { sk[i] = b; sk[l] = a; }
        }
      }
      __syncthreads();
    }
  }
}

// ---------------- kernels ----------------
__global__ void normalize_prep(const float* __restrict__ x, float* __restrict__ q,
                               ushort* __restrict__ qhi, ushort* __restrict__ qlo) {
  int b = blockIdx.x;
  int t = threadIdx.x;  // 64
  float a = x[(size_t)b * D + t];
  float c = x[(size_t)b * D + t + 64];
  float ss = a * a + c * c;
  for (int o = 32; o; o >>= 1) ss += __shfl_xor(ss, o);
  float inv = 1.0f / fmaxf(sqrtf(ss), 1e-12f);
  a *= inv; c *= inv;
  q[(size_t)b * D + t] = a;
  q[(size_t)b * D + t + 64] = c;
#pragma unroll
  for (int h = 0; h < 2; ++h) {
    int k = t + h * 64;
    float v = h ? c : a;
    int chunk = k >> 6, cc = (k >> 3) & 7, j = k & 7;
    int cd = cc ^ (b & 7);
    int pos = b * 128 + chunk * 64 + cd * 8 + j;
    ushort hb = bf16_rn(v);
    qhi[pos] = hb;
    qlo[pos] = bf16_rn(v - bf16_to_f(hb));
  }
}

// fused: out<-keys copy, keys hi/lo swizzled bf16 prep, values/age init
__global__ void prep_init(const float* __restrict__ keys, const int* __restrict__ values,
                          const float* __restrict__ age, float* __restrict__ out,
                          ushort* __restrict__ khi, ushort* __restrict__ klo) {
  size_t stride = (size_t)gridDim.x * blockDim.x;
  size_t t0 = (size_t)blockIdx.x * blockDim.x + threadIdx.x;
  size_t nslots = (size_t)M_SIZE * 16;
  for (size_t s = t0; s < nslots; s += stride) {
    int m = (int)(s >> 4);
    int sc = (int)(s & 15);
    int chunk = sc >> 3, c = sc & 7;
    int csrc = c ^ (m & 7);
    size_t src = (size_t)m * 128 + chunk * 64 + csrc * 8;
    float4 v0 = *(const float4*)(keys + src);
    float4 v1 = *(const float4*)(keys + src + 4);
    *(float4*)(out + OUT_KEYS + src) = v0;
    *(float4*)(out + OUT_KEYS + src + 4) = v1;
    size_t dst = (size_t)m * 128 + chunk * 64 + c * 8;
    float vv[8] = {v0.x, v0.y, v0.z, v0.w, v1.x, v1.y, v1.z, v1.w};
    ushort h[8], l[8];
#pragma unroll
    for (int e = 0; e < 8; ++e) {
      h[e] = bf16_rn(vv[e]);
      l[e] = bf16_rn(vv[e] - bf16_to_f(h[e]));
    }
    *(uint4*)(khi + dst) = *(uint4*)h;
    *(uint4*)(klo + dst) = *(uint4*)l;
  }
  for (size_t i = t0; i < (size_t)M_SIZE; i += stride) {
    out[OUT_VALUES + i] = (float)values[i];
    out[OUT_AGE + i] = age[i] + 1.0f;
  }
}

// 3-pass split-bf16 MFMA GEMM, fused candidate collection (no score matrix).
// block: 128 keys x 128 queries, 4 waves (2x2), wave tile 64x64 via 2x2 mfma_f32_32x32x16_bf16.
// grid: x = query-tiles (8)  -> consecutive blocks share the K-tile (L2/L3 reuse),
//       y = key-tiles (2048)
#define SEG 24
__global__ __launch_bounds__(256, 2) void gemm_topk(
    const ushort* __restrict__ khi, const ushort* __restrict__ klo,
    const ushort* __restrict__ qhi, const ushort* __restrict__ qlo,
    u64* __restrict__ cand, int* __restrict__ cnts) {
  __shared__ __align__(16) char lds[65536];
  char* KH = lds;
  char* KL = lds + 16384;
  char* QH = lds + 32768;
  char* QL = lds + 49152;
  const int g0 = blockIdx.x * 128;
  const int m0 = blockIdx.y * 128;
  const int tid = threadIdx.x;
  const int w = tid >> 6;
  const int lane = tid & 63;
  const int wm = w & 1;
  const int wq = w >> 1;

  f32x16 acc[2][2];
#pragma unroll
  for (int i = 0; i < 2; ++i)
#pragma unroll
    for (int j = 0; j < 2; ++j)
#pragma unroll
      for (int e = 0; e < 16; ++e) acc[i][j][e] = 0.f;

  for (int kc = 0; kc < 2; ++kc) {
    if (kc) __syncthreads();
    // stage 4 planes of [128 rows][64 bf16] via global_load_lds (pre-swizzled source)
#pragma unroll
    for (int it = 0; it < 4; ++it) {
      int blk = w * 4 + it;
      int rr = blk * 8 + (lane >> 3);
      int cc = lane & 7;
      size_t kidx = (size_t)(m0 + rr) * 128 + kc * 64 + cc * 8;
      size_t qidx = (size_t)(g0 + rr) * 128 + kc * 64 + cc * 8;
      int lo = blk * 1024;
      gload16(khi + kidx, KH + lo);
      gload16(klo + kidx, KL + lo);
      gload16(qhi + qidx, QH + lo);
      gload16(qlo + qidx, QL + lo);
    }
    __syncthreads();
#pragma unroll
    for (int ks = 0; ks < 4; ++ks) {
      bf16x8 aH[2], aL[2], bH[2], bL[2];
      int kb = ks * 32 + ((lane >> 5) << 4);
#pragma unroll
      for (int i = 0; i < 2; ++i) {
        int row = wm * 64 + i * 32 + (lane & 31);
        int off = row * 128 + (kb ^ ((row & 7) << 4));
        aH[i] = *(const bf16x8*)(KH + off);
        aL[i] = *(const bf16x8*)(KL + off);
      }
#pragma unroll
      for (int j = 0; j < 2; ++j) {
        int row = wq * 64 + j * 32 + (lane & 31);
        int off = row * 128 + (kb ^ ((row & 7) << 4));
        bH[j] = *(const bf16x8*)(QH + off);
        bL[j] = *(const bf16x8*)(QL + off);
      }
#pragma unroll
      for (int i = 0; i < 2; ++i)
#pragma unroll
        for (int j = 0; j < 2; ++j) {
          acc[i][j] = __builtin_amdgcn_mfma_f32_32x32x16_bf16(aH[i], bH[j], acc[i][j], 0, 0, 0);
          acc[i][j] = __builtin_amdgcn_mfma_f32_32x32x16_bf16(aH[i], bL[j], acc[i][j], 0, 0, 0);
          acc[i][j] = __builtin_amdgcn_mfma_f32_32x32x16_bf16(aL[i], bH[j], acc[i][j], 0, 0, 0);
        }
    }
  }

  // epilogue: LDS-local per-g compaction, then ONE global atomic per g per block.
  __syncthreads();  // all MFMA LDS reads done; safe to reuse lds
  int* lcnt = (int*)lds;            // 128 ints
  u64* lbuf = (u64*)(lds + 512);    // 128*SEG u64 = 24576 B
  for (int t = tid; t < 128; t += 256) lcnt[t] = 0;
  __syncthreads();
  // C/D: col(query)=lane&31, row(key)=(reg&3)+8*(reg>>2)+4*(lane>>5)
#pragma unroll
  for (int i = 0; i < 2; ++i)
#pragma unroll
    for (int j = 0; j < 2; ++j) {
      int lg = wq * 64 + j * 32 + (lane & 31);
      int mbase = m0 + wm * 64 + i * 32 + 4 * (lane >> 5);
#pragma unroll
      for (int r16 = 0; r16 < 16; ++r16) {
        float v = acc[i][j][r16];
        if (v > T0_SCORE) {
          int m = mbase + (r16 & 3) + 8 * (r16 >> 2);
          int slot = atomicAdd(&lcnt[lg], 1);
          if (slot < SEG) {
            lbuf[lg * SEG + slot] = packvi(v, m);
          } else {  // overflow (astronomically rare): direct global
            int gs = atomicAdd(&cnts[g0 + lg], 1);
            if (gs < CAP) cand[(size_t)(g0 + lg) * CAP + gs] = packvi(v, m);
          }
        }
      }
    }
  __syncthreads();
  if (tid < 128) {
    int lc = lcnt[tid];
    if (lc > SEG) lc = SEG;
    if (lc > 0) {
      int g = g0 + tid;
      int base = atomicAdd(&cnts[g], lc);
      for (int s = 0; s < lc; ++s) {
        int p = base + s;
        if (p < CAP) cand[(size_t)g * CAP + p] = lbuf[tid * SEG + s];
      }
    }
  }
}

struct SelShared {
  union {
    u64 sk[CAP];
    TS ts;
  } u;
  alignas(16) float qrow[D];
  float red[12];
  float ex8[8];
  int exi8[8];
  int besti;
};

__global__ __launch_bounds__(256) void select_scores(
    const u64* __restrict__ cand, const int* __restrict__ cnts,
    const float* __restrict__ q, const float* __restrict__ keys,
    const int* __restrict__ values, const int* __restrict__ y,
    float* __restrict__ out, int* __restrict__ yidx, int* __restrict__ resf,
    int* __restrict__ anyinc) {
  __shared__ SelShared sh;
  const int b = blockIdx.x;
  const int tid = threadIdx.x;
  const int n = cnts[b];
  const bool good = (n >= K_TOP && n <= CAP);

  for (int t = tid; t < D; t += 256) sh.qrow[t] = q[(size_t)b * D + t];
  __syncthreads();

  float v;
  int idx;
  float mx;
  if (good) {
    for (int t = tid; t < n; t += 256) sh.u.sk[t] = cand[(size_t)b * CAP + t];
    for (int t = n + tid; t < CAP; t += 256) sh.u.sk[t] = 0ull;
    __syncthreads();
    bitonic4096_desc(sh.u.sk, tid);
    u64 kk = sh.u.sk[tid];
    v = unmono((u32)(kk >> 32));
    idx = (int)(~(u32)kk);
    mx = unmono((u32)(sh.u.sk[0] >> 32));
    // exact f32 recompute of top-8 -> argmax robustness
    if (tid < 8) {
      int m = (int)(~(u32)sh.u.sk[tid]);
      DotScore ds{sh.qrow, keys};
      sh.ex8[tid] = ds(m);
      sh.exi8[tid] = m;
    }
    __syncthreads();
    if (tid == 0) {
      float bs = sh.ex8[0];
      int bm = sh.exi8[0];
      for (int t = 1; t < 8; ++t) {
        if (sh.ex8[t] > bs || (sh.ex8[t] == bs && sh.exi8[t] < bm)) {
          bs = sh.ex8[t]; bm = sh.exi8[t];
        }
      }
      sh.besti = bm;
    }
  } else {
    // fallback: exact full recompute selection (never expected to trigger)
    DotScore ds{sh.qrow, keys};
    topk_select_f(ds, M_SIZE, K_TOP, sh.u.ts);
    v = sh.u.ts.bufv[tid];
    idx = sh.u.ts.bufi[tid];
    mx = sh.u.ts.bufv[0];
    if (tid == 0) sh.besti = sh.u.ts.bufi[0];
  }
  __syncthreads();

  // softmax over sorted top-K
  float e = expf(TEMP * (v - mx));
  float se = e;
  for (int o = 32; o; o >>= 1) se += __shfl_xor(se, o);
  if ((tid & 63) == 0) sh.red[tid >> 6] = se;
  __syncthreads();
  float tot = sh.red[0] + sh.red[1] + sh.red[2] + sh.red[3];
  out[OUT_SOFTMAX + (size_t)b * K_TOP + tid] = e / tot;

  int val = values[idx];
  int yb = y[b];
  float mval = (val == yb) ? 1.0f : 0.0f;
  float p = v * mval;
  float ng = v * (1.0f - mval);
  for (int o = 32; o; o >>= 1) {
    p = fmaxf(p, __shfl_xor(p, o));
    ng = fmaxf(ng, __shfl_xor(ng, o));
  }
  if ((tid & 63) == 0) { sh.red[4 + (tid >> 6)] = p; sh.red[8 + (tid >> 6)] = ng; }
  __syncthreads();
  if (tid == 0) {
    float pos = fmaxf(fmaxf(sh.red[4], sh.red[5]), fmaxf(sh.red[6], sh.red[7]));
    float neg = fmaxf(fmaxf(sh.red[8], sh.red[9]), fmaxf(sh.red[10], sh.red[11]));
    float lt = fmaxf(neg - pos + MARGIN, 0.0f) * (1.0f / B);
    atomicAdd(&out[OUT_LOSS], lt);
    int i0 = sh.besti;
    int v0 = values[i0];
    out[OUT_YHAT + b] = (float)v0;
    yidx[b] = i0;
    int r = (v0 == yb) ? 1 : 0;
    resf[b] = r;
    if (!r) atomicOr(anyinc, 1);
  }
}

__global__ void winner_kernel(const int* __restrict__ yidx, int* __restrict__ winner) {
  __shared__ int sidx[B];
  int t = threadIdx.x;  // 1024
  sidx[t] = yidx[t];
  __syncthreads();
  int my = sidx[t];
  int w = 1;
  for (int b2 = t + 1; b2 < B; b2++)
    if (sidx[b2] == my) { w = 0; break; }
  winner[t] = w;
}

__global__ void cand_scatter_kernel(const float* __restrict__ keys, const float* __restrict__ q,
                                    const int* __restrict__ yidx, const int* __restrict__ resf,
                                    const int* __restrict__ winner, float* __restrict__ out) {
  int b = blockIdx.x;
  if (!winner[b] || !resf[b]) return;
  int t = threadIdx.x;  // 64
  int idx = yidx[b];
  float a = keys[(size_t)idx * D + t] + q[(size_t)b * D + t];
  float c = keys[(size_t)idx * D + t + 64] + q[(size_t)b * D + t + 64];
  float ss = a * a + c * c;
  for (int o = 32; o; o >>= 1) ss += __shfl_xor(ss, o);
  float inv = 1.0f / fmaxf(sqrtf(ss), 1e-12f);
  out[OUT_KEYS + (size_t)idx * D + t] = a * inv;
  out[OUT_KEYS + (size_t)idx * D + t + 64] = c * inv;
  if (t == 0) out[OUT_AGE + idx] = 0.0f;
}

__global__ void agenoise_kernel(const float* __restrict__ out, const float* __restrict__ noise,
                                float* __restrict__ an) {
  size_t stride = (size_t)gridDim.x * blockDim.x;
  for (size_t i = (size_t)blockIdx.x * blockDim.x + threadIdx.x; i < (size_t)M_SIZE; i += stride)
    an[i] = out[OUT_AGE + i] + noise[i];
}

__global__ void age_collect(const float* __restrict__ an, u64* __restrict__ cand,
                            int* __restrict__ cnt) {
  __shared__ int lcnt;
  __shared__ int gbase;
  __shared__ u64 lbuf[128];
  if (threadIdx.x == 0) lcnt = 0;
  __syncthreads();
  size_t stride = (size_t)gridDim.x * blockDim.x;
  for (size_t i = (size_t)blockIdx.x * blockDim.x + threadIdx.x; i < (size_t)M_SIZE; i += stride) {
    float v = an[i];
    if (v > T0_AGE) {
      int s = atomicAdd(&lcnt, 1);
      if (s < 128) lbuf[s] = packvi(v, (int)i);
      else {
        int gs = atomicAdd(cnt, 1);
        if (gs < CAP) cand[gs] = packvi(v, (int)i);
      }
    }
  }
  __syncthreads();
  int lc = lcnt;
  if (lc > 128) lc = 128;
  if (threadIdx.x == 0 && lc > 0) gbase = atomicAdd(cnt, lc);
  __syncthreads();
  if (lc > 0)
    for (int s = threadIdx.x; s < lc; s += blockDim.x) {
      int p = gbase + s;
      if (p < CAP) cand[p] = lbuf[s];
    }
}

struct AgeShared {
  union {
    u64 sk[CAP];
    TS ts;
  } u;
};

__global__ __launch_bounds__(256) void age_select(const float* __restrict__ an,
                                                  const u64* __restrict__ cand,
                                                  const int* __restrict__ cnt,
                                                  int* __restrict__ oldest) {
  __shared__ AgeShared sh;
  const int tid = threadIdx.x;
  const int n = *cnt;
  if (n >= B && n <= CAP) {
    for (int t = tid; t < n; t += 256) sh.u.sk[t] = cand[t];
    for (int t = n + tid; t < CAP; t += 256) sh.u.sk[t] = 0ull;
    __syncthreads();
    bitonic4096_desc(sh.u.sk, tid);
    for (int t = tid; t < B; t += 256) oldest[t] = (int)(~(u32)sh.u.sk[t]);
  } else {
    AnScore as{an};
    topk_select_f(as, M_SIZE, B, sh.u.ts);
    for (int t = tid; t < B; t += 256) oldest[t] = sh.u.ts.bufi[t];
  }
}

__global__ void scatter_old_kernel(const int* __restrict__ anyinc, const int* __restrict__ oldest,
                                   const float* __restrict__ q, const int* __restrict__ y,
                                   float* __restrict__ out) {
  if (*anyinc == 0) return;
  int j = blockIdx.x;
  int t = threadIdx.x;  // 64
  int o = oldest[j];
  out[OUT_KEYS + (size_t)o * D + t] = q[(size_t)j * D + t];
  out[OUT_KEYS + (size_t)o * D + t + 64] = q[(size_t)j * D + t + 64];
  if (t == 0) {
    out[OUT_VALUES + o] = (float)y[j];
    out[OUT_AGE + o] = 0.0f;
  }
}

extern "C" void kernel_launch(void* const* d_in, const int* in_sizes, int n_in,
                              void* d_out, int out_size, void* d_ws, size_t ws_size,
                              hipStream_t stream) {
  const float* x = (const float*)d_in[0];
  const int* y = (const int*)d_in[1];
  const float* keys = (const float*)d_in[2];
  const int* values = (const int*)d_in[3];
  const float* age = (const float*)d_in[4];
  const float* noise = (const float*)d_in[5];
  float* out = (float*)d_out;

  float* ws = (float*)d_ws;
  float* q = ws + WS_Q;
  int* yidx = (int*)(ws + WS_YIDX);
  int* resf = (int*)(ws + WS_RESF);
  int* winner = (int*)(ws + WS_WINNER);
  int* anyinc = (int*)(ws + WS_ANYINC);
  int* oldest = (int*)(ws + WS_OLDEST);
  int* cnts = (int*)(ws + WS_CNTS);
  int* cntage = (int*)(ws + WS_CNTAGE);
  float* an = ws + WS_AN;
  ushort* qhi = (ushort*)(ws + WS_QHI);
  ushort* qlo = (ushort*)(ws + WS_QLO);
  ushort* khi = (ushort*)(ws + WS_KHI);
  ushort* klo = (ushort*)(ws + WS_KLO);
  u64* cands = (u64*)(ws + WS_CANDS);
  u64* candage = (u64*)(ws + WS_CANDAGE);

  hipMemsetAsync(out + OUT_LOSS, 0, sizeof(float), stream);
  hipMemsetAsync(anyinc, 0, sizeof(int), stream);
  hipMemsetAsync(cnts, 0, B * sizeof(int), stream);
  hipMemsetAsync(cntage, 0, sizeof(int), stream);

  normalize_prep<<<B, 64, 0, stream>>>(x, q, qhi, qlo);
  prep_init<<<4096, 256, 0, stream>>>(keys, values, age, out, khi, klo);
  gemm_topk<<<dim3(B / 128, M_SIZE / 128), 256, 0, stream>>>(khi, klo, qhi, qlo, cands, cnts);
  select_scores<<<B, 256, 0, stream>>>(cands, cnts, q, keys, values, y, out, yidx, resf, anyinc);
  winner_kernel<<<1, 1024, 0, stream>>>(yidx, winner);
  cand_scatter_kernel<<<B, 64, 0, stream>>>(keys, q, yidx, resf, winner, out);
  agenoise_kernel<<<512, 256, 0, stream>>>(out, noise, an);
  age_collect<<<256, 256, 0, stream>>>(an, candage, cntage);
  age_select<<<1, 256, 0, stream>>>(an, candage, cntage, oldest);
  scatter_old_kernel<<<B, 64, 0, stream>>>(anyinc, oldest, q, y, out);
}